// Round 9
// baseline (307.022 us; speedup 1.0000x reference)
//
#include <hip/hip_runtime.h>
#include <hip/hip_bf16.h>
#include <cstdint>
#include <cstddef>

// B=1, T=2048, D=1024, E=8, F=2048, K=2. fp32 in/out; bf16 MFMA internally.
#define N_TOK 2048
#define DIM   1024
#define NEXP  8
#define FDIM  2048

#define BM 128
#define BN 128
#define BK 64

typedef __attribute__((ext_vector_type(8))) short short8;   // 8 x bf16
typedef __attribute__((ext_vector_type(4))) float f32x4;    // MFMA C/D + native vec loads
typedef __attribute__((ext_vector_type(2))) unsigned int uint2v;
typedef unsigned short ushort_t;

// ---- workspace layout (bytes) ----
#define OFF_COUNTS  0
#define OFF_TOK     4096
#define OFF_GATE    (OFF_TOK + NEXP * N_TOK * 4)
#define OFF_A       ((size_t)1 << 20)                              // Abuf bf16: 16 MiB
#define OFF_W1B     (OFF_A  + (size_t)2 * N_TOK * FDIM * 2)        // W1 bf16: 32 MiB
#define OFF_W2B     (OFF_W1B + (size_t)NEXP * FDIM * DIM * 2)      // W2 bf16: 32 MiB
#define OFF_XB      (OFF_W2B + (size_t)NEXP * DIM * FDIM * 2)      // x bf16: 4 MiB
// total ~85.1 MiB

__device__ __forceinline__ uint32_t cvt2(float lo, float hi) {
  __hip_bfloat162 p = __float22bfloat162_rn(make_float2(lo, hi));
  uint32_t r; __builtin_memcpy(&r, &p, 4); return r;
}

// async global->LDS, 16B per lane; LDS dest is wave-uniform base + lane*16
__device__ __forceinline__ void gl16(const ushort_t* g, const ushort_t* l) {
  __builtin_amdgcn_global_load_lds(
      (const __attribute__((address_space(1))) void*)g,
      (__attribute__((address_space(3))) void*)l, 16, 0, 0);
}

// bijective XCD-chunked swizzle (m204)
__device__ __forceinline__ int xcd_swz(int bid, int nwg) {
  int q = nwg >> 3, r = nwg & 7;
  int xcd = bid & 7, local = bid >> 3;
  int base = (xcd < r) ? xcd * (q + 1) : r * (q + 1) + (xcd - r) * q;
  return base + local;
}

// ---------------- prep: fp32 -> bf16, dense f32x4 nt loads + uint2 stores ----------------
// blocks [0,2048) -> W1, [2048,4096) -> W2, [4096,4352) -> x; 2048 f32x4 per block
__global__ __launch_bounds__(256) void prep_kernel(
    const float* __restrict__ W1, const float* __restrict__ W2, const float* __restrict__ x,
    ushort_t* __restrict__ W1b, ushort_t* __restrict__ W2b, ushort_t* __restrict__ xb) {
  int b = blockIdx.x;
  const f32x4* s; uint2v* d; size_t off;   // off in float4 units
  if (b < 2048)      { s = (const f32x4*)W1; d = (uint2v*)W1b; off = (size_t)b * 2048; }
  else if (b < 4096) { s = (const f32x4*)W2; d = (uint2v*)W2b; off = (size_t)(b - 2048) * 2048; }
  else               { s = (const f32x4*)x;  d = (uint2v*)xb;  off = (size_t)(b - 4096) * 2048; }
  s += off; d += off;
  int tid = threadIdx.x;
  f32x4 v[8];
#pragma unroll
  for (int k = 0; k < 8; ++k) v[k] = __builtin_nontemporal_load(&s[tid + k * 256]);
#pragma unroll
  for (int k = 0; k < 8; ++k) {
    uint2v o; o.x = cvt2(v[k].x, v[k].y); o.y = cvt2(v[k].z, v[k].w);
    d[tid + k * 256] = o;
  }
}

// ---------------- router: 4 waves/block, 1 wave per token (fp32, exact) ----------------
__global__ __launch_bounds__(256) void router_kernel(
    const float* __restrict__ x, const float* __restrict__ Wr,
    int* __restrict__ counts, int* __restrict__ toklist,
    float* __restrict__ gatelist) {
  int n = blockIdx.x * 4 + (threadIdx.x >> 6);
  int lane = threadIdx.x & 63;
  const float* xr = x + (size_t)n * DIM;

  float xv[DIM / 64];
#pragma unroll
  for (int i = 0; i < DIM / 64; ++i) xv[i] = xr[lane + 64 * i];

  float logit[NEXP];
#pragma unroll
  for (int e = 0; e < NEXP; ++e) {
    const float* wr = Wr + (size_t)e * DIM;
    float s = 0.f;
#pragma unroll
    for (int i = 0; i < DIM / 64; ++i) s += xv[i] * wr[lane + 64 * i];
#pragma unroll
    for (int off = 32; off; off >>= 1) s += __shfl_down(s, off);
    logit[e] = s;
  }

  if (lane == 0) {
    float m = logit[0];
#pragma unroll
    for (int e = 1; e < NEXP; ++e) m = fmaxf(m, logit[e]);
    float p[NEXP];
#pragma unroll
    for (int e = 0; e < NEXP; ++e) p[e] = expf(logit[e] - m);
    int i1 = 0;
#pragma unroll
    for (int e = 1; e < NEXP; ++e) if (p[e] > p[i1]) i1 = e;
    int i2 = (i1 == 0) ? 1 : 0;
#pragma unroll
    for (int e = 0; e < NEXP; ++e)
      if (e != i1 && p[e] > p[i2]) i2 = e;
    float denom = p[i1] + p[i2];

    int pos1 = atomicAdd(&counts[i1], 1);
    toklist[i1 * N_TOK + pos1] = n;
    gatelist[i1 * N_TOK + pos1] = p[i1] / denom;

    int pos2 = atomicAdd(&counts[i2], 1);
    toklist[i2 * N_TOK + pos2] = n;
    gatelist[i2 * N_TOK + pos2] = p[i2] / denom;
  }
}

// ---------------- fc1: Abuf[base+r, f] = relu(xb[tok[r],:] . W1b[e,f,:])^2 ----------------
// 128x128x64 tile, DOUBLE-buffered gload_lds staging, counted vmcnt(8) pipeline,
// source-side XOR swizzle (col16 ^= row&7), 4 waves 2x2.
__global__ __launch_bounds__(256, 2) void fc1_mfma(
    const ushort_t* __restrict__ xb, const ushort_t* __restrict__ W1b,
    const int* __restrict__ counts, const int* __restrict__ toklist,
    __hip_bfloat16* __restrict__ Abuf) {
  const int ROWB = N_TOK / BM;     // 16
  const int COLB = FDIM / BN;      // 16
  int bid = xcd_swz(blockIdx.x, NEXP * ROWB * COLB);
  int e  = bid / (ROWB * COLB);
  int rb = (bid / COLB) % ROWB;
  int cb = bid % COLB;
  int ne = counts[e];
  if (rb * BM >= ne) return;
  int base = 0;
  for (int i = 0; i < e; ++i) base += counts[i];

  __shared__ ushort_t As[2][BM * BK];   // 2 x 16 KiB
  __shared__ ushort_t Bs[2][BN * BK];   // 2 x 16 KiB

  int tid = threadIdx.x, lane = tid & 63, w = tid >> 6;

  const ushort_t* gA[4]; const ushort_t* gB[4];
#pragma unroll
  for (int i = 0; i < 4; ++i) {
    int row = w * 32 + i * 8 + (lane >> 3);
    int c16 = (lane & 7) ^ (row & 7);
    int r = rb * BM + row; if (r >= ne) r = ne - 1;
    int tok = toklist[e * N_TOK + r];
    gA[i] = xb + (size_t)tok * DIM + c16 * 8;
    gB[i] = W1b + ((size_t)e * FDIM + cb * BN + row) * DIM + c16 * 8;
  }

  int wr = (w >> 1) * 64, wc = (w & 1) * 64;
  int lr = lane & 15, lg = lane >> 4;
  f32x4 acc[4][4] = {};

#define ISSUE(buf, t) do { _Pragma("unroll") for (int i = 0; i < 4; ++i) { \
    gl16(gA[i] + (size_t)(t) * BK, &As[buf][w * 2048 + i * 512]); \
    gl16(gB[i] + (size_t)(t) * BK, &Bs[buf][w * 2048 + i * 512]); } } while (0)

  const int NT = DIM / BK;   // 16
  asm volatile("s_waitcnt vmcnt(0)" ::: "memory");   // anchor vmcnt counting
  ISSUE(0, 0);
  for (int t = 0; t < NT; ++t) {
    int cur = t & 1;
    if (t + 1 < NT) {
      ISSUE(cur ^ 1, t + 1);
      asm volatile("s_waitcnt vmcnt(8)" ::: "memory");   // tile t landed; t+1 in flight
    } else {
      asm volatile("s_waitcnt vmcnt(0)" ::: "memory");
    }
    __builtin_amdgcn_sched_barrier(0);
    __builtin_amdgcn_s_barrier();
#pragma unroll
    for (int ks = 0; ks < 2; ++ks) {
      short8 af[4], bf[4];
#pragma unroll
      for (int m = 0; m < 4; ++m) {
        int row = wr + m * 16 + lr;
        af[m] = *(const short8*)&As[cur][row * BK + (((ks * 4 + lg) ^ (row & 7)) * 8)];
      }
#pragma unroll
      for (int n = 0; n < 4; ++n) {
        int row = wc + n * 16 + lr;
        bf[n] = *(const short8*)&Bs[cur][row * BK + (((ks * 4 + lg) ^ (row & 7)) * 8)];
      }
#pragma unroll
      for (int m = 0; m < 4; ++m)
#pragma unroll
        for (int n = 0; n < 4; ++n)
          acc[m][n] = __builtin_amdgcn_mfma_f32_16x16x32_bf16(af[m], bf[n], acc[m][n], 0, 0, 0);
    }
    asm volatile("s_waitcnt lgkmcnt(0)" ::: "memory");   // all ds_reads of buf done
    __builtin_amdgcn_sched_barrier(0);
    __builtin_amdgcn_s_barrier();                        // buf free for re-stage
  }
#undef ISSUE

  int colbase = cb * BN + wc + lr;
#pragma unroll
  for (int m = 0; m < 4; ++m) {
#pragma unroll
    for (int j = 0; j < 4; ++j) {
      int r = rb * BM + wr + m * 16 + lg * 4 + j;
      if (r < ne) {
        __hip_bfloat16* orow = Abuf + (size_t)(base + r) * FDIM + colbase;
#pragma unroll
        for (int n = 0; n < 4; ++n) {
          float v = fmaxf(acc[m][n][j], 0.f);
          orow[n * 16] = __float2bfloat16(v * v);
        }
      }
    }
  }
}

// ---------------- fc2 (split-K x2): out[tok,d] += g * (Abuf[base+r, ks0:+1024] . W2b[e,d,ks0:]) ----------------
__global__ __launch_bounds__(256, 2) void fc2_mfma(
    const ushort_t* __restrict__ Abuf, const ushort_t* __restrict__ W2b,
    const int* __restrict__ counts, const int* __restrict__ toklist,
    const float* __restrict__ gatelist, float* __restrict__ out) {
  const int ROWB = N_TOK / BM;     // 16
  const int COLB = DIM / BN;       // 8
  int bid = xcd_swz(blockIdx.x, NEXP * ROWB * COLB);
  int e  = bid / (ROWB * COLB);
  int rb = (bid / COLB) % ROWB;
  int cb = bid % COLB;
  int ks0 = blockIdx.y * (FDIM / 2);   // 0 or 1024
  int ne = counts[e];
  if (rb * BM >= ne) return;
  int base = 0;
  for (int i = 0; i < e; ++i) base += counts[i];

  __shared__ ushort_t As[2][BM * BK];
  __shared__ ushort_t Bs[2][BN * BK];

  int tid = threadIdx.x, lane = tid & 63, w = tid >> 6;

  const ushort_t* gA[4]; const ushort_t* gB[4];
#pragma unroll
  for (int i = 0; i < 4; ++i) {
    int row = w * 32 + i * 8 + (lane >> 3);
    int c16 = (lane & 7) ^ (row & 7);
    int r = rb * BM + row; if (r >= ne) r = ne - 1;
    gA[i] = Abuf + (size_t)(base + r) * FDIM + ks0 + c16 * 8;
    gB[i] = W2b + ((size_t)e * DIM + cb * BN + row) * FDIM + ks0 + c16 * 8;
  }

  int wr = (w >> 1) * 64, wc = (w & 1) * 64;
  int lr = lane & 15, lg = lane >> 4;
  f32x4 acc[4][4] = {};

#define ISSUE(buf, t) do { _Pragma("unroll") for (int i = 0; i < 4; ++i) { \
    gl16(gA[i] + (size_t)(t) * BK, &As[buf][w * 2048 + i * 512]); \
    gl16(gB[i] + (size_t)(t) * BK, &Bs[buf][w * 2048 + i * 512]); } } while (0)

  const int NT = (FDIM / 2) / BK;   // 16
  asm volatile("s_waitcnt vmcnt(0)" ::: "memory");
  ISSUE(0, 0);
  for (int t = 0; t < NT; ++t) {
    int cur = t & 1;
    if (t + 1 < NT) {
      ISSUE(cur ^ 1, t + 1);
      asm volatile("s_waitcnt vmcnt(8)" ::: "memory");
    } else {
      asm volatile("s_waitcnt vmcnt(0)" ::: "memory");
    }
    __builtin_amdgcn_sched_barrier(0);
    __builtin_amdgcn_s_barrier();
#pragma unroll
    for (int ks = 0; ks < 2; ++ks) {
      short8 af[4], bf[4];
#pragma unroll
      for (int m = 0; m < 4; ++m) {
        int row = wr + m * 16 + lr;
        af[m] = *(const short8*)&As[cur][row * BK + (((ks * 4 + lg) ^ (row & 7)) * 8)];
      }
#pragma unroll
      for (int n = 0; n < 4; ++n) {
        int row = wc + n * 16 + lr;
        bf[n] = *(const short8*)&Bs[cur][row * BK + (((ks * 4 + lg) ^ (row & 7)) * 8)];
      }
#pragma unroll
      for (int m = 0; m < 4; ++m)
#pragma unroll
        for (int n = 0; n < 4; ++n)
          acc[m][n] = __builtin_amdgcn_mfma_f32_16x16x32_bf16(af[m], bf[n], acc[m][n], 0, 0, 0);
    }
    asm volatile("s_waitcnt lgkmcnt(0)" ::: "memory");
    __builtin_amdgcn_sched_barrier(0);
    __builtin_amdgcn_s_barrier();
  }
#undef ISSUE

  // epilogue: gated atomic accumulate into out (out pre-zeroed)
  int colbase = cb * BN + wc + lr;
#pragma unroll
  for (int m = 0; m < 4; ++m) {
#pragma unroll
    for (int j = 0; j < 4; ++j) {
      int r = rb * BM + wr + m * 16 + lg * 4 + j;
      if (r < ne) {
        int tok = toklist[e * N_TOK + r];
        float g = gatelist[e * N_TOK + r];
        float* orow = out + (size_t)tok * DIM + colbase;
#pragma unroll
        for (int n = 0; n < 4; ++n)
          atomicAdd(&orow[n * 16], g * acc[m][n][j]);
      }
    }
  }
}

extern "C" void kernel_launch(void* const* d_in, const int* in_sizes, int n_in,
                              void* d_out, int out_size, void* d_ws, size_t ws_size,
                              hipStream_t stream) {
  const float* x  = (const float*)d_in[0];
  const float* Wr = (const float*)d_in[1];
  const float* W1 = (const float*)d_in[2];
  const float* W2 = (const float*)d_in[3];
  float* out = (float*)d_out;

  char* ws = (char*)d_ws;
  int*   counts   = (int*)(ws + OFF_COUNTS);
  int*   toklist  = (int*)(ws + OFF_TOK);
  float* gatelist = (float*)(ws + OFF_GATE);
  __hip_bfloat16* Abuf = (__hip_bfloat16*)(ws + OFF_A);
  ushort_t* W1b = (ushort_t*)(ws + OFF_W1B);
  ushort_t* W2b = (ushort_t*)(ws + OFF_W2B);
  ushort_t* xb  = (ushort_t*)(ws + OFF_XB);

  (void)hipMemsetAsync(counts, 0, NEXP * sizeof(int), stream);
  (void)hipMemsetAsync(out, 0, (size_t)out_size * sizeof(float), stream);

  prep_kernel<<<4352, 256, 0, stream>>>(W1, W2, x, W1b, W2b, xb);

  router_kernel<<<N_TOK / 4, 256, 0, stream>>>(x, Wr, counts, toklist, gatelist);

  fc1_mfma<<<NEXP * (N_TOK / BM) * (FDIM / BN), 256, 0, stream>>>(
      xb, W1b, counts, toklist, Abuf);

  fc2_mfma<<<dim3(NEXP * (N_TOK / BM) * (DIM / BN), 2), 256, 0, stream>>>(
      (const ushort_t*)Abuf, W2b, counts, toklist, gatelist, out);
}

// Round 11
// 290.589 us; speedup vs baseline: 1.0565x; 1.0565x over previous
//
#include <hip/hip_runtime.h>
#include <hip/hip_bf16.h>
#include <cstdint>
#include <cstddef>

// B=1, T=2048, D=1024, E=8, F=2048, K=2. fp32 in/out; bf16 MFMA internally.
#define N_TOK 2048
#define DIM   1024
#define NEXP  8
#define FDIM  2048

#define BM 128
#define BN 128
#define BK 32

typedef __attribute__((ext_vector_type(8))) short short8;   // 8 x bf16
typedef __attribute__((ext_vector_type(4))) float f32x4;    // MFMA C/D + native vec loads
typedef __attribute__((ext_vector_type(2))) unsigned int uint2v;
typedef unsigned short ushort_t;

// ---- workspace layout (bytes) ----
#define OFF_COUNTS  0
#define OFF_TOK     4096
#define OFF_GATE    (OFF_TOK + NEXP * N_TOK * 4)
#define OFF_A       ((size_t)1 << 20)                              // Abuf bf16: 16 MiB
#define OFF_W1B     (OFF_A  + (size_t)2 * N_TOK * FDIM * 2)        // W1 bf16: 32 MiB
#define OFF_W2B     (OFF_W1B + (size_t)NEXP * FDIM * DIM * 2)      // W2 bf16: 32 MiB
#define OFF_XB      (OFF_W2B + (size_t)NEXP * DIM * FDIM * 2)      // x bf16: 4 MiB
// total ~85.1 MiB

__device__ __forceinline__ uint32_t cvt2(float lo, float hi) {
  __hip_bfloat162 p = __float22bfloat162_rn(make_float2(lo, hi));
  uint32_t r; __builtin_memcpy(&r, &p, 4); return r;
}

// async global->LDS, 16B per lane; LDS dest is wave-uniform base + lane*16
__device__ __forceinline__ void gl16(const ushort_t* g, const ushort_t* l) {
  __builtin_amdgcn_global_load_lds(
      (const __attribute__((address_space(1))) void*)g,
      (__attribute__((address_space(3))) void*)l, 16, 0, 0);
}

// bijective XCD-chunked swizzle (m204)
__device__ __forceinline__ int xcd_swz(int bid, int nwg) {
  int q = nwg >> 3, r = nwg & 7;
  int xcd = bid & 7, local = bid >> 3;
  int base = (xcd < r) ? xcd * (q + 1) : r * (q + 1) + (xcd - r) * q;
  return base + local;
}

// ---------------- prep: fp32 -> bf16 + zero out + zero counts (one launch) ----------------
// blocks [0,2048) -> W1, [2048,4096) -> W2, [4096,4352) -> x, [4352,4608) -> zero out,
// block 4608 -> zero counts.
__global__ __launch_bounds__(256) void prep_kernel(
    const float* __restrict__ W1, const float* __restrict__ W2, const float* __restrict__ x,
    ushort_t* __restrict__ W1b, ushort_t* __restrict__ W2b, ushort_t* __restrict__ xb,
    float* __restrict__ out, int* __restrict__ counts) {
  int b = blockIdx.x;
  int tid = threadIdx.x;
  if (b >= 4352) {
    if (b == 4608) {
      if (tid < NEXP) counts[tid] = 0;
      return;
    }
    // zero out: 256 blocks x 2048 float4 each = 2M floats
    f32x4* o = (f32x4*)out + (size_t)(b - 4352) * 2048;
    f32x4 z = {0.f, 0.f, 0.f, 0.f};
#pragma unroll
    for (int k = 0; k < 8; ++k) o[tid + k * 256] = z;
    return;
  }
  const f32x4* s; uint2v* d; size_t off;   // off in float4 units
  if (b < 2048)      { s = (const f32x4*)W1; d = (uint2v*)W1b; off = (size_t)b * 2048; }
  else if (b < 4096) { s = (const f32x4*)W2; d = (uint2v*)W2b; off = (size_t)(b - 2048) * 2048; }
  else               { s = (const f32x4*)x;  d = (uint2v*)xb;  off = (size_t)(b - 4096) * 2048; }
  s += off; d += off;
  f32x4 v[8];
#pragma unroll
  for (int k = 0; k < 8; ++k) v[k] = __builtin_nontemporal_load(&s[tid + k * 256]);
#pragma unroll
  for (int k = 0; k < 8; ++k) {
    uint2v o; o.x = cvt2(v[k].x, v[k].y); o.y = cvt2(v[k].z, v[k].w);
    d[tid + k * 256] = o;
  }
}

// ---------------- router: 4 waves/block, 1 wave per token (fp32, exact) ----------------
__global__ __launch_bounds__(256) void router_kernel(
    const float* __restrict__ x, const float* __restrict__ Wr,
    int* __restrict__ counts, int* __restrict__ toklist,
    float* __restrict__ gatelist) {
  int n = blockIdx.x * 4 + (threadIdx.x >> 6);
  int lane = threadIdx.x & 63;
  const float* xr = x + (size_t)n * DIM;

  float xv[DIM / 64];
#pragma unroll
  for (int i = 0; i < DIM / 64; ++i) xv[i] = xr[lane + 64 * i];

  float logit[NEXP];
#pragma unroll
  for (int e = 0; e < NEXP; ++e) {
    const float* wr = Wr + (size_t)e * DIM;
    float s = 0.f;
#pragma unroll
    for (int i = 0; i < DIM / 64; ++i) s += xv[i] * wr[lane + 64 * i];
#pragma unroll
    for (int off = 32; off; off >>= 1) s += __shfl_down(s, off);
    logit[e] = s;
  }

  if (lane == 0) {
    float m = logit[0];
#pragma unroll
    for (int e = 1; e < NEXP; ++e) m = fmaxf(m, logit[e]);
    float p[NEXP];
#pragma unroll
    for (int e = 0; e < NEXP; ++e) p[e] = expf(logit[e] - m);
    int i1 = 0;
#pragma unroll
    for (int e = 1; e < NEXP; ++e) if (p[e] > p[i1]) i1 = e;
    int i2 = (i1 == 0) ? 1 : 0;
#pragma unroll
    for (int e = 0; e < NEXP; ++e)
      if (e != i1 && p[e] > p[i2]) i2 = e;
    float denom = p[i1] + p[i2];

    int pos1 = atomicAdd(&counts[i1], 1);
    toklist[i1 * N_TOK + pos1] = n;
    gatelist[i1 * N_TOK + pos1] = p[i1] / denom;

    int pos2 = atomicAdd(&counts[i2], 1);
    toklist[i2 * N_TOK + pos2] = n;
    gatelist[i2 * N_TOK + pos2] = p[i2] / denom;
  }
}

// ---------------- fc1: Abuf[base+r, f] = relu(xb[tok[r],:] . W1b[e,f,:])^2 ----------------
// 128x128x32 tile, dbuf gload_lds, counted vmcnt(4), 32KB LDS -> 4 blocks/CU.
// LDS rows are 64B; swizzle: 16B slot s holds global slot s^(row&3).
__global__ __launch_bounds__(256, 4) void fc1_mfma(
    const ushort_t* __restrict__ xb, const ushort_t* __restrict__ W1b,
    const int* __restrict__ counts, const int* __restrict__ toklist,
    __hip_bfloat16* __restrict__ Abuf) {
  const int ROWB = N_TOK / BM;     // 16
  const int COLB = FDIM / BN;      // 16
  int bid = xcd_swz(blockIdx.x, NEXP * ROWB * COLB);
  int e  = bid / (ROWB * COLB);
  int rb = (bid / COLB) % ROWB;
  int cb = bid % COLB;
  int ne = counts[e];
  if (rb * BM >= ne) return;
  int base = 0;
  for (int i = 0; i < e; ++i) base += counts[i];

  __shared__ ushort_t As[2][BM * BK];   // 2 x 8 KiB
  __shared__ ushort_t Bs[2][BN * BK];   // 2 x 8 KiB

  int tid = threadIdx.x, lane = tid & 63, w = tid >> 6;

  // staging: wave w covers rows [w*32, w*32+32); gl16 i covers 16 rows.
  // lane -> row = w*32 + i*16 + (lane>>2), slot = lane&3; src slot = slot^(row&3).
  const ushort_t* gA[2]; const ushort_t* gB[2];
#pragma unroll
  for (int i = 0; i < 2; ++i) {
    int row = w * 32 + i * 16 + (lane >> 2);
    int sl  = (lane & 3) ^ (row & 3);
    int r = rb * BM + row; if (r >= ne) r = ne - 1;
    int tok = toklist[e * N_TOK + r];
    gA[i] = xb + (size_t)tok * DIM + sl * 8;
    gB[i] = W1b + ((size_t)e * FDIM + cb * BN + row) * DIM + sl * 8;
  }

  int wr = (w >> 1) * 64, wc = (w & 1) * 64;
  int lr = lane & 15, lg = lane >> 4;
  f32x4 acc[4][4] = {};

#define ISSUE(buf, t) do { _Pragma("unroll") for (int i = 0; i < 2; ++i) { \
    gl16(gA[i] + (size_t)(t) * BK, &As[buf][w * 1024 + i * 512]); \
    gl16(gB[i] + (size_t)(t) * BK, &Bs[buf][w * 1024 + i * 512]); } } while (0)

  const int NT = DIM / BK;   // 32
  asm volatile("s_waitcnt vmcnt(0)" ::: "memory");
  ISSUE(0, 0);
  for (int t = 0; t < NT; ++t) {
    int cur = t & 1;
    if (t + 1 < NT) {
      ISSUE(cur ^ 1, t + 1);
      asm volatile("s_waitcnt vmcnt(4)" ::: "memory");   // tile t landed; t+1 in flight
    } else {
      asm volatile("s_waitcnt vmcnt(0)" ::: "memory");
    }
    __builtin_amdgcn_sched_barrier(0);
    __builtin_amdgcn_s_barrier();
    {
      short8 af[4], bf[4];
#pragma unroll
      for (int m = 0; m < 4; ++m) {
        int row = wr + m * 16 + lr;
        af[m] = *(const short8*)&As[cur][row * BK + ((lg ^ (row & 3)) * 8)];
      }
#pragma unroll
      for (int n = 0; n < 4; ++n) {
        int row = wc + n * 16 + lr;
        bf[n] = *(const short8*)&Bs[cur][row * BK + ((lg ^ (row & 3)) * 8)];
      }
#pragma unroll
      for (int m = 0; m < 4; ++m)
#pragma unroll
        for (int n = 0; n < 4; ++n)
          acc[m][n] = __builtin_amdgcn_mfma_f32_16x16x32_bf16(af[m], bf[n], acc[m][n], 0, 0, 0);
    }
    asm volatile("s_waitcnt lgkmcnt(0)" ::: "memory");
    __builtin_amdgcn_sched_barrier(0);
    __builtin_amdgcn_s_barrier();
  }
#undef ISSUE

  int colbase = cb * BN + wc + lr;
#pragma unroll
  for (int m = 0; m < 4; ++m) {
#pragma unroll
    for (int j = 0; j < 4; ++j) {
      int r = rb * BM + wr + m * 16 + lg * 4 + j;
      if (r < ne) {
        __hip_bfloat16* orow = Abuf + (size_t)(base + r) * FDIM + colbase;
#pragma unroll
        for (int n = 0; n < 4; ++n) {
          float v = fmaxf(acc[m][n][j], 0.f);
          orow[n * 16] = __float2bfloat16(v * v);
        }
      }
    }
  }
}

// ---------------- fc2 (split-K x2): out[tok,d] += g * (Abuf[base+r, ks0:+1024] . W2b[e,d,ks0:]) ----------------
__global__ __launch_bounds__(256, 4) void fc2_mfma(
    const ushort_t* __restrict__ Abuf, const ushort_t* __restrict__ W2b,
    const int* __restrict__ counts, const int* __restrict__ toklist,
    const float* __restrict__ gatelist, float* __restrict__ out) {
  const int ROWB = N_TOK / BM;     // 16
  const int COLB = DIM / BN;       // 8
  int bid = xcd_swz(blockIdx.x, NEXP * ROWB * COLB);
  int e  = bid / (ROWB * COLB);
  int rb = (bid / COLB) % ROWB;
  int cb = bid % COLB;
  int ks0 = blockIdx.y * (FDIM / 2);   // 0 or 1024
  int ne = counts[e];
  if (rb * BM >= ne) return;
  int base = 0;
  for (int i = 0; i < e; ++i) base += counts[i];

  __shared__ ushort_t As[2][BM * BK];
  __shared__ ushort_t Bs[2][BN * BK];

  int tid = threadIdx.x, lane = tid & 63, w = tid >> 6;

  const ushort_t* gA[2]; const ushort_t* gB[2];
#pragma unroll
  for (int i = 0; i < 2; ++i) {
    int row = w * 32 + i * 16 + (lane >> 2);
    int sl  = (lane & 3) ^ (row & 3);
    int r = rb * BM + row; if (r >= ne) r = ne - 1;
    gA[i] = Abuf + (size_t)(base + r) * FDIM + ks0 + sl * 8;
    gB[i] = W2b + ((size_t)e * DIM + cb * BN + row) * FDIM + ks0 + sl * 8;
  }

  int wr = (w >> 1) * 64, wc = (w & 1) * 64;
  int lr = lane & 15, lg = lane >> 4;
  f32x4 acc[4][4] = {};

#define ISSUE(buf, t) do { _Pragma("unroll") for (int i = 0; i < 2; ++i) { \
    gl16(gA[i] + (size_t)(t) * BK, &As[buf][w * 1024 + i * 512]); \
    gl16(gB[i] + (size_t)(t) * BK, &Bs[buf][w * 1024 + i * 512]); } } while (0)

  const int NT = (FDIM / 2) / BK;   // 32
  asm volatile("s_waitcnt vmcnt(0)" ::: "memory");
  ISSUE(0, 0);
  for (int t = 0; t < NT; ++t) {
    int cur = t & 1;
    if (t + 1 < NT) {
      ISSUE(cur ^ 1, t + 1);
      asm volatile("s_waitcnt vmcnt(4)" ::: "memory");
    } else {
      asm volatile("s_waitcnt vmcnt(0)" ::: "memory");
    }
    __builtin_amdgcn_sched_barrier(0);
    __builtin_amdgcn_s_barrier();
    {
      short8 af[4], bf[4];
#pragma unroll
      for (int m = 0; m < 4; ++m) {
        int row = wr + m * 16 + lr;
        af[m] = *(const short8*)&As[cur][row * BK + ((lg ^ (row & 3)) * 8)];
      }
#pragma unroll
      for (int n = 0; n < 4; ++n) {
        int row = wc + n * 16 + lr;
        bf[n] = *(const short8*)&Bs[cur][row * BK + ((lg ^ (row & 3)) * 8)];
      }
#pragma unroll
      for (int m = 0; m < 4; ++m)
#pragma unroll
        for (int n = 0; n < 4; ++n)
          acc[m][n] = __builtin_amdgcn_mfma_f32_16x16x32_bf16(af[m], bf[n], acc[m][n], 0, 0, 0);
    }
    asm volatile("s_waitcnt lgkmcnt(0)" ::: "memory");
    __builtin_amdgcn_sched_barrier(0);
    __builtin_amdgcn_s_barrier();
  }
#undef ISSUE

  // epilogue: gated atomic accumulate into out (out pre-zeroed by prep)
  int colbase = cb * BN + wc + lr;
#pragma unroll
  for (int m = 0; m < 4; ++m) {
#pragma unroll
    for (int j = 0; j < 4; ++j) {
      int r = rb * BM + wr + m * 16 + lg * 4 + j;
      if (r < ne) {
        int tok = toklist[e * N_TOK + r];
        float g = gatelist[e * N_TOK + r];
        float* orow = out + (size_t)tok * DIM + colbase;
#pragma unroll
        for (int n = 0; n < 4; ++n)
          atomicAdd(&orow[n * 16], g * acc[m][n][j]);
      }
    }
  }
}

extern "C" void kernel_launch(void* const* d_in, const int* in_sizes, int n_in,
                              void* d_out, int out_size, void* d_ws, size_t ws_size,
                              hipStream_t stream) {
  const float* x  = (const float*)d_in[0];
  const float* Wr = (const float*)d_in[1];
  const float* W1 = (const float*)d_in[2];
  const float* W2 = (const float*)d_in[3];
  float* out = (float*)d_out;

  char* ws = (char*)d_ws;
  int*   counts   = (int*)(ws + OFF_COUNTS);
  int*   toklist  = (int*)(ws + OFF_TOK);
  float* gatelist = (float*)(ws + OFF_GATE);
  __hip_bfloat16* Abuf = (__hip_bfloat16*)(ws + OFF_A);
  ushort_t* W1b = (ushort_t*)(ws + OFF_W1B);
  ushort_t* W2b = (ushort_t*)(ws + OFF_W2B);
  ushort_t* xb  = (ushort_t*)(ws + OFF_XB);

  prep_kernel<<<4609, 256, 0, stream>>>(W1, W2, x, W1b, W2b, xb, out, counts);

  router_kernel<<<N_TOK / 4, 256, 0, stream>>>(x, Wr, counts, toklist, gatelist);

  fc1_mfma<<<NEXP * (N_TOK / BM) * (FDIM / BN), 256, 0, stream>>>(
      xb, W1b, counts, toklist, Abuf);

  fc2_mfma<<<dim3(NEXP * (N_TOK / BM) * (DIM / BN), 2), 256, 0, stream>>>(
      (const ushort_t*)Abuf, W2b, counts, toklist, gatelist, out);
}